// Round 1
// baseline (1964.504 us; speedup 1.0000x reference)
//
#include <hip/hip_runtime.h>
#include <cstdint>
#include <cstddef>

#define USER_N 40000
#define ITEM_N 40000
#define NN     80000
#define DD     128
#define KK     16
#define EE     1600000

static __device__ __forceinline__ float4 ld4(const float* p){ return *(const float4*)p; }

// ---------------- init: e = concat(user_emb, item_emb); total(d_out) = e ----------------
__global__ void init_e_total(const float* __restrict__ user_emb, const float* __restrict__ item_emb,
                             float* __restrict__ e, float* __restrict__ total){
  int idx = blockIdx.x*blockDim.x + threadIdx.x;           // float4 index
  const int n4 = NN*DD/4;
  if (idx >= n4) return;
  const int u4 = USER_N*DD/4;
  float4 v = (idx < u4) ? ((const float4*)user_emb)[idx] : ((const float4*)item_emb)[idx - u4];
  ((float4*)e)[idx] = v;
  ((float4*)total)[idx] = v;
}

// ---------------- CSR build ----------------
__global__ void hist_rows(const int* __restrict__ rows, int* __restrict__ counts){
  int i = blockIdx.x*blockDim.x + threadIdx.x;
  if (i < EE) atomicAdd(&counts[rows[i]], 1);
}

__global__ void scan_rowptr(const int* __restrict__ counts, int* __restrict__ row_ptr,
                            int* __restrict__ cursor){
  const int T = 1024;
  const int CH = (NN + T - 1)/T;  // 79
  __shared__ int ssum[T];
  int tid = threadIdx.x;
  int begin = tid*CH;
  int end = begin + CH; if (end > NN) end = NN;
  int s = 0;
  for (int r = begin; r < end; r++) s += counts[r];
  ssum[tid] = s;
  __syncthreads();
  for (int off = 1; off < T; off <<= 1){
    int t = (tid >= off) ? ssum[tid-off] : 0;
    __syncthreads();
    ssum[tid] += t;
    __syncthreads();
  }
  int run = ssum[tid] - s;   // exclusive prefix of this chunk
  for (int r = begin; r < end; r++){
    row_ptr[r] = run; cursor[r] = run; run += counts[r];
  }
  if (tid == T-1) row_ptr[NN] = ssum[T-1];
}

__global__ void scatter_edges(const int* __restrict__ rows, const int* __restrict__ cols,
                              const float* __restrict__ vals, int* __restrict__ cursor,
                              int* __restrict__ csr_col, float* __restrict__ csr_val){
  int i = blockIdx.x*blockDim.x + threadIdx.x;
  if (i >= EE) return;
  int r = rows[i];
  int p = atomicAdd(&cursor[r], 1);
  csr_col[p] = cols[i];
  csr_val[p] = vals[i];
}

// ---------------- SpMM: one wave per row, float2 per lane ----------------
__global__ __launch_bounds__(256) void spmm_kernel(const int* __restrict__ row_ptr,
    const int* __restrict__ csr_col, const float* __restrict__ csr_val,
    const float* __restrict__ ein, float* __restrict__ tmp){
  int wid  = (blockIdx.x*blockDim.x + threadIdx.x) >> 6;
  int lane = threadIdx.x & 63;
  if (wid >= NN) return;
  int s = row_ptr[wid], t = row_ptr[wid+1];
  const float2* E2 = (const float2*)ein;
  float ax = 0.f, ay = 0.f;
  int e = s;
  for (; e + 1 < t; e += 2){
    int c0 = csr_col[e], c1 = csr_col[e+1];
    float v0 = csr_val[e], v1 = csr_val[e+1];
    float2 x0 = E2[(size_t)c0*64 + lane];
    float2 x1 = E2[(size_t)c1*64 + lane];
    ax += v0*x0.x + v1*x1.x;
    ay += v0*x0.y + v1*x1.y;
  }
  if (e < t){
    int c0 = csr_col[e]; float v0 = csr_val[e];
    float2 x0 = E2[(size_t)c0*64 + lane];
    ax += v0*x0.x; ay += v0*x0.y;
  }
  ((float2*)tmp)[(size_t)wid*64 + lane] = make_float2(ax, ay);
}

// ---------------- pos tables: pos_emb @ W.T + b for Q/K/V, u/i ----------------
// layout: posK_u[17*128] | posV_u[17*128] | posK_i | posV_i | posQ_u[128] | posQ_i[128]
__global__ void pos_proj(const float* __restrict__ pos_emb,
                         const float* __restrict__ u_in_w, const float* __restrict__ u_in_b,
                         const float* __restrict__ i_in_w, const float* __restrict__ i_in_b,
                         float* __restrict__ pt){
  int j = blockIdx.x;      // 0..16
  int m = blockIdx.y;      // 0..5
  int d = threadIdx.x;     // 0..127
  if (m >= 4 && j > 0) return;
  const float* w; const float* b; float* out; int roff;
  switch (m){
    case 0: w=u_in_w; b=u_in_b; roff=128; out=pt + j*128;            break; // posK_u
    case 1: w=u_in_w; b=u_in_b; roff=256; out=pt + 17*128 + j*128;   break; // posV_u
    case 2: w=i_in_w; b=i_in_b; roff=128; out=pt + 2*17*128 + j*128; break; // posK_i
    case 3: w=i_in_w; b=i_in_b; roff=256; out=pt + 3*17*128 + j*128; break; // posV_i
    case 4: w=u_in_w; b=u_in_b; roff=0;   out=pt + 4*17*128;         break; // posQ_u
    default:w=i_in_w; b=i_in_b; roff=0;   out=pt + 4*17*128 + 128;   break; // posQ_i
  }
  int row = roff + d;
  float acc = b[row];
  for (int c = 0; c < DD; c++) acc += pos_emb[j*DD + c] * w[row*DD + c];
  out[d] = acc;
}

// ---------------- tiled GEMM: C[r][d] = sum_c A[r][c]*W[d][c], rows [base,base+cnt) -----
// optional epilogue: C = acc + bias + resid;  total += C   (out-projection path)
__global__ __launch_bounds__(256,2) void gemm128(const float* __restrict__ A,
    const float* __restrict__ W, float* __restrict__ C, int base, int cnt,
    const float* __restrict__ bias, const float* __restrict__ resid, float* total){
  __shared__ float As[64][128];   // As[k][r]
  __shared__ float Ws[64][128];   // Ws[k][d]
  int tid = threadIdx.x;
  int w = tid >> 6, l = tid & 63;
  int r0 = ((((w>>1)<<3) + (l>>3)) << 3);   // 8 distinct per wave -> 2-way LDS alias (free)
  int d0 = ((((w&1)<<3) + (l&7)) << 3);
  int rowBase = base + blockIdx.x*128;
  float acc[8][8];
  #pragma unroll
  for (int i=0;i<8;i++)
    #pragma unroll
    for (int j=0;j<8;j++) acc[i][j] = 0.f;

  for (int ks = 0; ks < DD; ks += 64){
    #pragma unroll
    for (int i=0;i<8;i++){                 // A tile: 128 rows x 64 cols
      int q = tid + i*256;
      int r = q >> 4;
      int c4 = (q & 15) << 2;
      int grow = rowBase + r;
      float4 v = (grow - base < cnt) ? ld4(A + (size_t)grow*DD + ks + c4)
                                     : make_float4(0.f,0.f,0.f,0.f);
      As[c4+0][r]=v.x; As[c4+1][r]=v.y; As[c4+2][r]=v.z; As[c4+3][r]=v.w;
    }
    #pragma unroll
    for (int i=0;i<8;i++){                 // W tile: 128 d x 64 c (transposed to Ws[c][d])
      int q = tid + i*256;
      int d = q >> 4;
      int c4 = (q & 15) << 2;
      float4 v = ld4(W + (size_t)d*DD + ks + c4);
      Ws[c4+0][d]=v.x; Ws[c4+1][d]=v.y; Ws[c4+2][d]=v.z; Ws[c4+3][d]=v.w;
    }
    __syncthreads();
    #pragma unroll 8
    for (int k=0;k<64;k++){
      float a[8], b[8];
      *(float4*)&a[0] = *(const float4*)&As[k][r0];
      *(float4*)&a[4] = *(const float4*)&As[k][r0+4];
      *(float4*)&b[0] = *(const float4*)&Ws[k][d0];
      *(float4*)&b[4] = *(const float4*)&Ws[k][d0+4];
      #pragma unroll
      for (int i=0;i<8;i++)
        #pragma unroll
        for (int j=0;j<8;j++) acc[i][j] += a[i]*b[j];
    }
    __syncthreads();
  }

  if (resid){
    float4 b0 = ld4(bias + d0), b1 = ld4(bias + d0 + 4);
    #pragma unroll
    for (int i=0;i<8;i++){
      int grow = rowBase + r0 + i;
      if (grow - base >= cnt) continue;
      size_t co = (size_t)grow*DD + d0;
      float4 rv0 = ld4(resid + co), rv1 = ld4(resid + co + 4);
      float4 t0  = ld4(total + co), t1  = ld4(total + co + 4);
      float4 v0 = make_float4(acc[i][0]+b0.x+rv0.x, acc[i][1]+b0.y+rv0.y,
                              acc[i][2]+b0.z+rv0.z, acc[i][3]+b0.w+rv0.w);
      float4 v1 = make_float4(acc[i][4]+b1.x+rv1.x, acc[i][5]+b1.y+rv1.y,
                              acc[i][6]+b1.z+rv1.z, acc[i][7]+b1.w+rv1.w);
      *(float4*)(C + co)     = v0;
      *(float4*)(C + co + 4) = v1;
      t0.x+=v0.x; t0.y+=v0.y; t0.z+=v0.z; t0.w+=v0.w;
      t1.x+=v1.x; t1.y+=v1.y; t1.z+=v1.z; t1.w+=v1.w;
      *(float4*)(total + co)     = t0;
      *(float4*)(total + co + 4) = t1;
    }
  } else {
    #pragma unroll
    for (int i=0;i<8;i++){
      int grow = rowBase + r0 + i;
      if (grow - base >= cnt) continue;
      size_t co = (size_t)grow*DD + d0;
      *(float4*)(C + co)     = make_float4(acc[i][0],acc[i][1],acc[i][2],acc[i][3]);
      *(float4*)(C + co + 4) = make_float4(acc[i][4],acc[i][5],acc[i][6],acc[i][7]);
    }
  }
}

// ---------------- attention: one wave per node, L=17, H=4, dh=32 ----------------
__global__ __launch_bounds__(256) void attn_kernel(const float* QP,
    const float* __restrict__ KP, const float* __restrict__ VP,
    const int* __restrict__ samples,
    const float* __restrict__ posQ, const float* __restrict__ posK, const float* __restrict__ posV,
    float* O, int base, int cnt){
  int wid  = (blockIdx.x*blockDim.x + threadIdx.x) >> 6;
  int lane = threadIdx.x & 63;
  if (wid >= cnt) return;
  int n = base + wid;
  const float2* QP2 = (const float2*)QP;
  const float2* KP2 = (const float2*)KP;
  const float2* VP2 = (const float2*)VP;
  const float2* pQ2 = (const float2*)posQ;
  const float2* pK2 = (const float2*)posK;
  const float2* pV2 = (const float2*)posV;
  float2 pq = pQ2[lane];
  float2 qv = QP2[(size_t)n*64 + lane];
  float qx = qv.x + pq.x, qy = qv.y + pq.y;
  int smp = (lane < KK) ? samples[(size_t)n*KK + lane] : 0;
  float sc[17], vx[17], vy[17];
  #pragma unroll
  for (int j=0;j<17;j++){
    int row = (j==0) ? n : __shfl(smp, j-1, 64);
    float2 k2 = KP2[(size_t)row*64 + lane];
    float2 pk = pK2[j*64 + lane];
    float2 v2 = VP2[(size_t)row*64 + lane];
    float2 pv = pV2[j*64 + lane];
    float kx = k2.x + pk.x, ky = k2.y + pk.y;
    vx[j] = v2.x + pv.x; vy[j] = v2.y + pv.y;
    float p = qx*kx + qy*ky;          // head = lane>>4 (dims 2*lane, 2*lane+1)
    p += __shfl_xor(p, 1, 64);
    p += __shfl_xor(p, 2, 64);
    p += __shfl_xor(p, 4, 64);
    p += __shfl_xor(p, 8, 64);
    sc[j] = p * 0.17677669529663687f; // 1/sqrt(32)
  }
  float m = sc[0];
  #pragma unroll
  for (int j=1;j<17;j++) m = fmaxf(m, sc[j]);
  float ssum = 0.f;
  #pragma unroll
  for (int j=0;j<17;j++){ sc[j] = __expf(sc[j]-m); ssum += sc[j]; }
  float inv = 1.f/ssum;
  float ox=0.f, oy=0.f;
  #pragma unroll
  for (int j=0;j<17;j++){ ox += sc[j]*vx[j]; oy += sc[j]*vy[j]; }
  ((float2*)O)[(size_t)n*64 + lane] = make_float2(ox*inv, oy*inv);
}

// ---------------- duplicate total into outputs 1,2 ----------------
__global__ void dup_out(float* __restrict__ out){
  int idx = blockIdx.x*blockDim.x + threadIdx.x;
  const int n4 = NN*DD/4;
  if (idx < n4){
    float4 v = ((const float4*)out)[idx];
    ((float4*)out)[n4 + idx] = v;
  }
}

extern "C" void kernel_launch(void* const* d_in, const int* in_sizes, int n_in,
                              void* d_out, int out_size, void* d_ws, size_t ws_size,
                              hipStream_t stream){
  const int*   adj_rows = (const int*)d_in[0];
  const int*   adj_cols = (const int*)d_in[1];
  const float* adj_vals = (const float*)d_in[2];
  const int*   samples  = (const int*)d_in[3];
  const float* user_emb = (const float*)d_in[4];
  const float* item_emb = (const float*)d_in[5];
  const float* pos_emb  = (const float*)d_in[6];
  const float* u_in_w   = (const float*)d_in[7];
  const float* u_in_b   = (const float*)d_in[8];
  const float* u_out_w  = (const float*)d_in[9];
  const float* u_out_b  = (const float*)d_in[10];
  const float* i_in_w   = (const float*)d_in[11];
  const float* i_in_b   = (const float*)d_in[12];
  const float* i_out_w  = (const float*)d_in[13];
  const float* i_out_b  = (const float*)d_in[14];
  float* out = (float*)d_out;

  char* ws = (char*)d_ws;
  size_t off = 0;
  auto alloc = [&](size_t bytes)->char*{
    char* p = ws + off; off += (bytes + 255) & ~(size_t)255; return p;
  };
  float* e       = (float*)alloc((size_t)NN*DD*4);
  float* tmp     = (float*)alloc((size_t)NN*DD*4);
  float* QP      = (float*)alloc((size_t)NN*DD*4);   // doubles as O (attn output)
  float* KP      = (float*)alloc((size_t)NN*DD*4);
  float* VP      = (float*)alloc((size_t)NN*DD*4);
  int*   csr_col = (int*)  alloc((size_t)EE*4);
  float* csr_val = (float*)alloc((size_t)EE*4);
  int*   counts  = (int*)  alloc((size_t)NN*4);
  int*   row_ptr = (int*)  alloc((size_t)(NN+1)*4);
  int*   cursor  = (int*)  alloc((size_t)NN*4);
  float* pt      = (float*)alloc((size_t)8960*4);

  float* posK_u = pt;
  float* posV_u = pt + 17*128;
  float* posK_i = pt + 2*17*128;
  float* posV_i = pt + 3*17*128;
  float* posQ_u = pt + 4*17*128;
  float* posQ_i = pt + 4*17*128 + 128;

  const float* wq_u = u_in_w;
  const float* wk_u = u_in_w + 128*128;
  const float* wv_u = u_in_w + 2*128*128;
  const float* wq_i = i_in_w;
  const float* wk_i = i_in_w + 128*128;
  const float* wv_i = i_in_w + 2*128*128;

  hipMemsetAsync(counts, 0, (size_t)NN*4, stream);
  init_e_total<<<NN*DD/4/256, 256, 0, stream>>>(user_emb, item_emb, e, out);
  hist_rows<<<(EE+255)/256, 256, 0, stream>>>(adj_rows, counts);
  scan_rowptr<<<1, 1024, 0, stream>>>(counts, row_ptr, cursor);
  scatter_edges<<<(EE+255)/256, 256, 0, stream>>>(adj_rows, adj_cols, adj_vals,
                                                  cursor, csr_col, csr_val);
  pos_proj<<<dim3(17,6), 128, 0, stream>>>(pos_emb, u_in_w, u_in_b, i_in_w, i_in_b, pt);

  for (int it = 0; it < 2; it++){
    spmm_kernel<<<NN/4, 256, 0, stream>>>(row_ptr, csr_col, csr_val, e, tmp);
    // Q projection (pos+bias folded into posQ tables, added in attn)
    gemm128<<<(USER_N+127)/128, 256, 0, stream>>>(tmp, wq_u, QP, 0,      USER_N, nullptr, nullptr, nullptr);
    gemm128<<<(ITEM_N+127)/128, 256, 0, stream>>>(tmp, wq_i, QP, USER_N, ITEM_N, nullptr, nullptr, nullptr);
    // ---- user half ----
    gemm128<<<(NN+127)/128, 256, 0, stream>>>(tmp, wk_u, KP, 0, NN, nullptr, nullptr, nullptr);
    gemm128<<<(NN+127)/128, 256, 0, stream>>>(tmp, wv_u, VP, 0, NN, nullptr, nullptr, nullptr);
    attn_kernel<<<USER_N/4, 256, 0, stream>>>(QP, KP, VP, samples, posQ_u, posK_u, posV_u,
                                              QP, 0, USER_N);
    gemm128<<<(USER_N+127)/128, 256, 0, stream>>>(QP, u_out_w, e, 0, USER_N, u_out_b, tmp, out);
    // ---- item half ----
    gemm128<<<(NN+127)/128, 256, 0, stream>>>(tmp, wk_i, KP, 0, NN, nullptr, nullptr, nullptr);
    gemm128<<<(NN+127)/128, 256, 0, stream>>>(tmp, wv_i, VP, 0, NN, nullptr, nullptr, nullptr);
    attn_kernel<<<ITEM_N/4, 256, 0, stream>>>(QP, KP, VP, samples, posQ_i, posK_i, posV_i,
                                              QP, USER_N, ITEM_N);
    gemm128<<<(ITEM_N+127)/128, 256, 0, stream>>>(QP, i_out_w, e, USER_N, ITEM_N, i_out_b, tmp, out);
  }
  dup_out<<<NN*DD/4/256, 256, 0, stream>>>(out);
}

// Round 2
// 1170.146 us; speedup vs baseline: 1.6789x; 1.6789x over previous
//
#include <hip/hip_runtime.h>
#include <hip/hip_bf16.h>
#include <cstdint>
#include <cstddef>

#define USER_N 40000
#define ITEM_N 40000
#define NN     80000
#define DD     128
#define KK     16
#define EE     1600000

typedef __attribute__((ext_vector_type(8))) short bf16x8;
typedef __attribute__((ext_vector_type(4))) float f32x4;
typedef unsigned short ushort_t;
typedef unsigned int   uint32;

static __device__ __forceinline__ float4 ld4(const float* p){ return *(const float4*)p; }
static __device__ __forceinline__ ushort_t f2bf(float x){
  __hip_bfloat16 h = __float2bfloat16(x);
  return *reinterpret_cast<ushort_t*>(&h);
}
static __device__ __forceinline__ float bflo(uint32 u){ return __uint_as_float(u << 16); }
static __device__ __forceinline__ float bfhi(uint32 u){ return __uint_as_float(u & 0xffff0000u); }

// ---------------- init: e_bf = bf16(concat(user,item)); total(d_out) = concat ----------------
__global__ void init_e_total(const float* __restrict__ user_emb, const float* __restrict__ item_emb,
                             ushort_t* __restrict__ e_bf, float* __restrict__ total){
  int idx = blockIdx.x*blockDim.x + threadIdx.x;           // float4 index
  const int n4 = NN*DD/4;
  if (idx >= n4) return;
  const int u4 = USER_N*DD/4;
  float4 v = (idx < u4) ? ((const float4*)user_emb)[idx] : ((const float4*)item_emb)[idx - u4];
  ((float4*)total)[idx] = v;
  ushort4 b; b.x = f2bf(v.x); b.y = f2bf(v.y); b.z = f2bf(v.z); b.w = f2bf(v.w);
  ((ushort4*)e_bf)[idx] = b;
}

// ---------------- weights -> bf16 ----------------
// layout: u_in (3*16384) | i_in (3*16384) | u_out (16384) | i_out (16384)
__global__ void cvt_weights(const float* __restrict__ u_in_w, const float* __restrict__ i_in_w,
                            const float* __restrict__ u_out_w, const float* __restrict__ i_out_w,
                            ushort_t* __restrict__ wbf){
  int i = blockIdx.x*256 + threadIdx.x;   // 512 blocks x 256 = 131072
  float v;
  if      (i < 49152)  v = u_in_w[i];
  else if (i < 98304)  v = i_in_w[i - 49152];
  else if (i < 114688) v = u_out_w[i - 98304];
  else                 v = i_out_w[i - 114688];
  wbf[i] = f2bf(v);
}

// ---------------- CSR build ----------------
__global__ void hist_rows(const int* __restrict__ rows, int* __restrict__ counts){
  int i = blockIdx.x*blockDim.x + threadIdx.x;
  if (i < EE) atomicAdd(&counts[rows[i]], 1);
}

__global__ void block_sum(const int* __restrict__ counts, int* __restrict__ bsum){
  __shared__ int s[256];
  int i = blockIdx.x*256 + threadIdx.x;
  s[threadIdx.x] = (i < NN) ? counts[i] : 0;
  __syncthreads();
  for (int o = 128; o > 0; o >>= 1){
    if (threadIdx.x < o) s[threadIdx.x] += s[threadIdx.x + o];
    __syncthreads();
  }
  if (threadIdx.x == 0) bsum[blockIdx.x] = s[0];
}

__global__ void scan_bsum(const int* __restrict__ bsum, int* __restrict__ bpre,
                          int* __restrict__ row_ptr){
  __shared__ int s[512];
  int v = (threadIdx.x < 313) ? bsum[threadIdx.x] : 0;
  s[threadIdx.x] = v;
  __syncthreads();
  for (int o = 1; o < 512; o <<= 1){
    int t = (threadIdx.x >= o) ? s[threadIdx.x - o] : 0;
    __syncthreads();
    s[threadIdx.x] += t;
    __syncthreads();
  }
  if (threadIdx.x < 313) bpre[threadIdx.x] = s[threadIdx.x] - v;
  if (threadIdx.x == 312) row_ptr[NN] = s[312];
}

__global__ void block_scan(const int* __restrict__ counts, const int* __restrict__ bpre,
                           int* __restrict__ row_ptr, int* __restrict__ cursor){
  __shared__ int s[256];
  int i = blockIdx.x*256 + threadIdx.x;
  int v = (i < NN) ? counts[i] : 0;
  s[threadIdx.x] = v;
  __syncthreads();
  for (int o = 1; o < 256; o <<= 1){
    int t = (threadIdx.x >= o) ? s[threadIdx.x - o] : 0;
    __syncthreads();
    s[threadIdx.x] += t;
    __syncthreads();
  }
  if (i < NN){
    int ex = bpre[blockIdx.x] + s[threadIdx.x] - v;
    row_ptr[i] = ex; cursor[i] = ex;
  }
}

__global__ void scatter_edges(const int* __restrict__ rows, const int* __restrict__ cols,
                              const float* __restrict__ vals, int* __restrict__ cursor,
                              int* __restrict__ csr_col, float* __restrict__ csr_val){
  int i = blockIdx.x*blockDim.x + threadIdx.x;
  if (i >= EE) return;
  int r = rows[i];
  int p = atomicAdd(&cursor[r], 1);
  csr_col[p] = cols[i];
  csr_val[p] = vals[i];
}

// ---------------- SpMM: one wave per row; bf16 gather (256B/row), fp32+bf16 outputs ----------
__global__ __launch_bounds__(256) void spmm_kernel(const int* __restrict__ row_ptr,
    const int* __restrict__ csr_col, const float* __restrict__ csr_val,
    const ushort_t* __restrict__ e_bf, float* __restrict__ tmp, ushort_t* __restrict__ tmp_bf){
  int wid  = (blockIdx.x*blockDim.x + threadIdx.x) >> 6;
  int lane = threadIdx.x & 63;
  if (wid >= NN) return;
  int s = row_ptr[wid], t = row_ptr[wid+1];
  const uint32* E = (const uint32*)e_bf;   // 2 bf16 per uint
  float ax = 0.f, ay = 0.f;
  int e = s;
  for (; e + 1 < t; e += 2){
    int c0 = csr_col[e], c1 = csr_col[e+1];
    float v0 = csr_val[e], v1 = csr_val[e+1];
    uint32 x0 = E[(size_t)c0*64 + lane];
    uint32 x1 = E[(size_t)c1*64 + lane];
    ax += v0*bflo(x0) + v1*bflo(x1);
    ay += v0*bfhi(x0) + v1*bfhi(x1);
  }
  if (e < t){
    int c0 = csr_col[e]; float v0 = csr_val[e];
    uint32 x0 = E[(size_t)c0*64 + lane];
    ax += v0*bflo(x0); ay += v0*bfhi(x0);
  }
  ((float2*)tmp)[(size_t)wid*64 + lane] = make_float2(ax, ay);
  uint32 o = (uint32)f2bf(ax) | ((uint32)f2bf(ay) << 16);
  ((uint32*)tmp_bf)[(size_t)wid*64 + lane] = o;
}

// ---------------- pos tables (fp32): pos_emb @ W.T + b for Q/K/V, u/i ----------------
__global__ void pos_proj(const float* __restrict__ pos_emb,
                         const float* __restrict__ u_in_w, const float* __restrict__ u_in_b,
                         const float* __restrict__ i_in_w, const float* __restrict__ i_in_b,
                         float* __restrict__ pt){
  int j = blockIdx.x;      // 0..16
  int m = blockIdx.y;      // 0..5
  int d = threadIdx.x;     // 0..127
  if (m >= 4 && j > 0) return;
  const float* w; const float* b; float* out; int roff;
  switch (m){
    case 0: w=u_in_w; b=u_in_b; roff=128; out=pt + j*128;            break; // posK_u
    case 1: w=u_in_w; b=u_in_b; roff=256; out=pt + 17*128 + j*128;   break; // posV_u
    case 2: w=i_in_w; b=i_in_b; roff=128; out=pt + 2*17*128 + j*128; break; // posK_i
    case 3: w=i_in_w; b=i_in_b; roff=256; out=pt + 3*17*128 + j*128; break; // posV_i
    case 4: w=u_in_w; b=u_in_b; roff=0;   out=pt + 4*17*128;         break; // posQ_u
    default:w=i_in_w; b=i_in_b; roff=0;   out=pt + 4*17*128 + 128;   break; // posQ_i
  }
  int row = roff + d;
  float acc = b[row];
  for (int c = 0; c < DD; c++) acc += pos_emb[j*DD + c] * w[row*DD + c];
  out[d] = acc;
}

// ---------------- MFMA GEMM: C[r][d] = sum_c A[r][c]*W[d][c], bf16 in, 128x128 tile ----------
// 4 waves; wave w: 32 rows (2 row-tiles of 16); 8 col-tiles of 16; K=128 in 4 chunks of 32.
// Frags loaded straight from global (A rows K-contig; W 32KB -> L1-resident).
// If resid != null: epilogue v = acc + bias + resid; Cbf = bf16(v); total += v; total2 = total.
__global__ __launch_bounds__(256) void gemm_bf(const ushort_t* __restrict__ A,
    const ushort_t* __restrict__ W, ushort_t* __restrict__ Cbf, int base, int cnt,
    const float* __restrict__ bias, const float* __restrict__ resid,
    float* __restrict__ total, float* __restrict__ total2){
  int tid = threadIdx.x;
  int wv = tid >> 6, l = tid & 63;
  int lr = l & 15, jg = l >> 4;
  int rowBase = base + blockIdx.x*128 + wv*32;
  const bf16x8* Av = (const bf16x8*)A;     // row stride 16 (x 16B)
  const bf16x8* Wv = (const bf16x8*)W;
  f32x4 acc[2][8];
  #pragma unroll
  for (int t=0;t<2;t++)
    #pragma unroll
    for (int c=0;c<8;c++) acc[t][c] = (f32x4){0.f,0.f,0.f,0.f};

  #pragma unroll
  for (int kc = 0; kc < 4; kc++){
    int ko = kc*4 + jg;                    // bf16x8 offset within a row
    bf16x8 a0 = {0,0,0,0,0,0,0,0}, a1 = {0,0,0,0,0,0,0,0};
    int r0 = rowBase + lr, r1 = rowBase + 16 + lr;
    if (r0 - base < cnt) a0 = Av[(size_t)r0*16 + ko];
    if (r1 - base < cnt) a1 = Av[(size_t)r1*16 + ko];
    bf16x8 b[8];
    #pragma unroll
    for (int ct=0;ct<8;ct++) b[ct] = Wv[(size_t)(ct*16 + lr)*16 + ko];
    #pragma unroll
    for (int ct=0;ct<8;ct++){
      acc[0][ct] = __builtin_amdgcn_mfma_f32_16x16x32_bf16(a0, b[ct], acc[0][ct], 0, 0, 0);
      acc[1][ct] = __builtin_amdgcn_mfma_f32_16x16x32_bf16(a1, b[ct], acc[1][ct], 0, 0, 0);
    }
  }

  // C/D layout: col = ct*16 + (lane&15), row = rowBase + t*16 + (lane>>4)*4 + reg
  if (!resid){
    #pragma unroll
    for (int t=0;t<2;t++)
      #pragma unroll
      for (int r=0;r<4;r++){
        int row = rowBase + t*16 + jg*4 + r;
        if (row - base >= cnt) continue;
        size_t ro = (size_t)row*128 + lr;
        #pragma unroll
        for (int ct=0;ct<8;ct++) Cbf[ro + ct*16] = f2bf(acc[t][ct][r]);
      }
  } else {
    float bi[8];
    #pragma unroll
    for (int ct=0;ct<8;ct++) bi[ct] = bias[ct*16 + lr];
    #pragma unroll
    for (int t=0;t<2;t++)
      #pragma unroll
      for (int r=0;r<4;r++){
        int row = rowBase + t*16 + jg*4 + r;
        if (row - base >= cnt) continue;
        size_t ro = (size_t)row*128 + lr;
        #pragma unroll
        for (int ct=0;ct<8;ct++){
          size_t o = ro + ct*16;
          float v = acc[t][ct][r] + bi[ct] + resid[o];
          Cbf[o] = f2bf(v);
          float tt = total[o] + v;
          total[o] = tt;
          if (total2) total2[o] = tt;
        }
      }
  }
}

// ---------------- attention: one wave per node, L=17, H=4, dh=32; bf16 Q/K/V --------------
__global__ __launch_bounds__(256) void attn_kernel(const ushort_t* __restrict__ QP,
    const ushort_t* __restrict__ KP, const ushort_t* __restrict__ VP,
    const int* __restrict__ samples,
    const float* __restrict__ posQ, const float* __restrict__ posK, const float* __restrict__ posV,
    ushort_t* __restrict__ O, int base, int cnt){
  int wid  = (blockIdx.x*blockDim.x + threadIdx.x) >> 6;
  int lane = threadIdx.x & 63;
  if (wid >= cnt) return;
  int n = base + wid;
  const uint32* Q2 = (const uint32*)QP;
  const uint32* K2 = (const uint32*)KP;
  const uint32* V2 = (const uint32*)VP;
  const float2* pQ2 = (const float2*)posQ;
  const float2* pK2 = (const float2*)posK;
  const float2* pV2 = (const float2*)posV;
  float2 pq = pQ2[lane];
  uint32 qu = Q2[(size_t)n*64 + lane];
  float qx = bflo(qu) + pq.x, qy = bfhi(qu) + pq.y;
  int smp = (lane < KK) ? samples[(size_t)n*KK + lane] : 0;
  float sc[17], vx[17], vy[17];
  #pragma unroll
  for (int j=0;j<17;j++){
    int row = (j==0) ? n : __shfl(smp, j-1, 64);
    uint32 ku = K2[(size_t)row*64 + lane];
    uint32 vu = V2[(size_t)row*64 + lane];
    float2 pk = pK2[j*64 + lane];
    float2 pv = pV2[j*64 + lane];
    float kx = bflo(ku) + pk.x, ky = bfhi(ku) + pk.y;
    vx[j] = bflo(vu) + pv.x; vy[j] = bfhi(vu) + pv.y;
    float p = qx*kx + qy*ky;              // head = lane>>4 (dims 2*lane, 2*lane+1)
    p += __shfl_xor(p, 1, 64);
    p += __shfl_xor(p, 2, 64);
    p += __shfl_xor(p, 4, 64);
    p += __shfl_xor(p, 8, 64);
    sc[j] = p * 0.17677669529663687f;     // 1/sqrt(32)
  }
  float m = sc[0];
  #pragma unroll
  for (int j=1;j<17;j++) m = fmaxf(m, sc[j]);
  float ssum = 0.f;
  #pragma unroll
  for (int j=0;j<17;j++){ sc[j] = __expf(sc[j]-m); ssum += sc[j]; }
  float inv = 1.f/ssum;
  float ox=0.f, oy=0.f;
  #pragma unroll
  for (int j=0;j<17;j++){ ox += sc[j]*vx[j]; oy += sc[j]*vy[j]; }
  uint32 o = (uint32)f2bf(ox*inv) | ((uint32)f2bf(oy*inv) << 16);
  ((uint32*)O)[(size_t)n*64 + lane] = o;
}

extern "C" void kernel_launch(void* const* d_in, const int* in_sizes, int n_in,
                              void* d_out, int out_size, void* d_ws, size_t ws_size,
                              hipStream_t stream){
  const int*   adj_rows = (const int*)d_in[0];
  const int*   adj_cols = (const int*)d_in[1];
  const float* adj_vals = (const float*)d_in[2];
  const int*   samples  = (const int*)d_in[3];
  const float* user_emb = (const float*)d_in[4];
  const float* item_emb = (const float*)d_in[5];
  const float* pos_emb  = (const float*)d_in[6];
  const float* u_in_w   = (const float*)d_in[7];
  const float* u_in_b   = (const float*)d_in[8];
  const float* u_out_w  = (const float*)d_in[9];
  const float* u_out_b  = (const float*)d_in[10];
  const float* i_in_w   = (const float*)d_in[11];
  const float* i_in_b   = (const float*)d_in[12];
  const float* i_out_w  = (const float*)d_in[13];
  const float* i_out_b  = (const float*)d_in[14];
  float* out = (float*)d_out;

  char* ws = (char*)d_ws;
  size_t off = 0;
  auto alloc = [&](size_t bytes)->char*{
    char* p = ws + off; off += (bytes + 255) & ~(size_t)255; return p;
  };
  float*    tmp     = (float*)   alloc((size_t)NN*DD*4);
  ushort_t* tmp_bf  = (ushort_t*)alloc((size_t)NN*DD*2);
  ushort_t* e_bf    = (ushort_t*)alloc((size_t)NN*DD*2);
  ushort_t* QPb     = (ushort_t*)alloc((size_t)NN*DD*2);
  ushort_t* KPb     = (ushort_t*)alloc((size_t)NN*DD*2);
  ushort_t* VPb     = (ushort_t*)alloc((size_t)NN*DD*2);
  ushort_t* Ob      = (ushort_t*)alloc((size_t)NN*DD*2);
  int*      csr_col = (int*)     alloc((size_t)EE*4);
  float*    csr_val = (float*)   alloc((size_t)EE*4);
  int*      counts  = (int*)     alloc((size_t)NN*4);
  int*      row_ptr = (int*)     alloc((size_t)(NN+1)*4);
  int*      cursor  = (int*)     alloc((size_t)NN*4);
  int*      bsum    = (int*)     alloc(320*4);
  int*      bpre    = (int*)     alloc(320*4);
  float*    pt      = (float*)   alloc((size_t)8960*4);
  ushort_t* wbf     = (ushort_t*)alloc((size_t)131072*2);

  float* posK_u = pt;
  float* posV_u = pt + 17*128;
  float* posK_i = pt + 2*17*128;
  float* posV_i = pt + 3*17*128;
  float* posQ_u = pt + 4*17*128;
  float* posQ_i = pt + 4*17*128 + 128;

  ushort_t* wq_u = wbf;
  ushort_t* wk_u = wbf + 16384;
  ushort_t* wv_u = wbf + 2*16384;
  ushort_t* wq_i = wbf + 3*16384;
  ushort_t* wk_i = wbf + 4*16384;
  ushort_t* wv_i = wbf + 5*16384;
  ushort_t* wo_u = wbf + 6*16384;
  ushort_t* wo_i = wbf + 7*16384;

  hipMemsetAsync(counts, 0, (size_t)NN*4, stream);
  init_e_total<<<NN*DD/4/256, 256, 0, stream>>>(user_emb, item_emb, e_bf, out);
  hist_rows<<<(EE+255)/256, 256, 0, stream>>>(adj_rows, counts);
  block_sum<<<313, 256, 0, stream>>>(counts, bsum);
  scan_bsum<<<1, 512, 0, stream>>>(bsum, bpre, row_ptr);
  block_scan<<<313, 256, 0, stream>>>(counts, bpre, row_ptr, cursor);
  scatter_edges<<<(EE+255)/256, 256, 0, stream>>>(adj_rows, adj_cols, adj_vals,
                                                  cursor, csr_col, csr_val);
  pos_proj<<<dim3(17,6), 128, 0, stream>>>(pos_emb, u_in_w, u_in_b, i_in_w, i_in_b, pt);
  cvt_weights<<<512, 256, 0, stream>>>(u_in_w, i_in_w, u_out_w, i_out_w, wbf);

  for (int it = 0; it < 2; it++){
    float* tot2 = (it == 1) ? (out + (size_t)NN*DD) : nullptr;
    spmm_kernel<<<NN/4, 256, 0, stream>>>(row_ptr, csr_col, csr_val, e_bf, tmp, tmp_bf);
    // Q projection (pos+bias folded into posQ tables, added in attn)
    gemm_bf<<<(USER_N+127)/128, 256, 0, stream>>>(tmp_bf, wq_u, QPb, 0,      USER_N, nullptr, nullptr, nullptr, nullptr);
    gemm_bf<<<(ITEM_N+127)/128, 256, 0, stream>>>(tmp_bf, wq_i, QPb, USER_N, ITEM_N, nullptr, nullptr, nullptr, nullptr);
    // ---- user half ----
    gemm_bf<<<(NN+127)/128, 256, 0, stream>>>(tmp_bf, wk_u, KPb, 0, NN, nullptr, nullptr, nullptr, nullptr);
    gemm_bf<<<(NN+127)/128, 256, 0, stream>>>(tmp_bf, wv_u, VPb, 0, NN, nullptr, nullptr, nullptr, nullptr);
    attn_kernel<<<USER_N/4, 256, 0, stream>>>(QPb, KPb, VPb, samples, posQ_u, posK_u, posV_u,
                                              Ob, 0, USER_N);
    gemm_bf<<<(USER_N+127)/128, 256, 0, stream>>>(Ob, wo_u, e_bf, 0, USER_N, u_out_b, tmp, out, tot2);
    // ---- item half ----
    gemm_bf<<<(NN+127)/128, 256, 0, stream>>>(tmp_bf, wk_i, KPb, 0, NN, nullptr, nullptr, nullptr, nullptr);
    gemm_bf<<<(NN+127)/128, 256, 0, stream>>>(tmp_bf, wv_i, VPb, 0, NN, nullptr, nullptr, nullptr, nullptr);
    attn_kernel<<<ITEM_N/4, 256, 0, stream>>>(QPb, KPb, VPb, samples, posQ_i, posK_i, posV_i,
                                              Ob, USER_N, ITEM_N);
    gemm_bf<<<(ITEM_N+127)/128, 256, 0, stream>>>(Ob, wo_i, e_bf, USER_N, ITEM_N, i_out_b, tmp, out, tot2);
  }
}